// Round 4
// baseline (811.470 us; speedup 1.0000x reference)
//
#include <hip/hip_runtime.h>
#include <hip/hip_fp16.h>
#include <stdint.h>

typedef _Float16 f16;
typedef _Float16 f16x8 __attribute__((ext_vector_type(8)));
typedef float f32x4 __attribute__((ext_vector_type(4)));

#define NB 32768      // batch
#define LAYERS 6
#define AK 160        // HALF + COND
#define HID 1024

// async global->LDS, 16B per lane. LDS dest is wave-uniform base + lane*16.
__device__ __forceinline__ void async_copy16(const void* g, void* l) {
  __builtin_amdgcn_global_load_lds(
      (const __attribute__((address_space(1))) void*)g,
      (__attribute__((address_space(3))) void*)l, 16, 0, 0);
}

// ---------------------------------------------------------------------------
// Fused prep: batch state + 3 weight transposes in one kernel (R9, validated).
// ---------------------------------------------------------------------------
__device__ __forceinline__ void wtrans_tile(const float* __restrict__ W,
                                            f16* __restrict__ Wt,
                                            const int K_, const int N_,
                                            const int bx, const int by,
                                            const int bz, float (*t)[65])
{
  const long off = (long)bz * K_ * N_;
  const float* Wl = W + off;
  f16* Wtl = Wt + off;
  const int k0 = by * 64, n0 = bx * 64;
  const int tx = threadIdx.x & 63, ty4 = threadIdx.x >> 6;
#pragma unroll
  for (int r = ty4; r < 64; r += 4) {
    const int k = k0 + r;
    if (k < K_) t[r][tx] = Wl[(long)k * N_ + n0 + tx];
  }
  __syncthreads();
  const int k = k0 + tx;
  if (k < K_) {
#pragma unroll
    for (int r = ty4; r < 64; r += 4) {
      const int n = n0 + r;
      Wtl[(long)n * K_ + k] = (f16)t[tx][r];
    }
  }
}

__global__ void prep_all(const float* __restrict__ T, const float* __restrict__ cond,
                         const float* __restrict__ W1, const float* __restrict__ W2,
                         const float* __restrict__ W3,
                         float* __restrict__ z, float* __restrict__ ld,
                         f16* __restrict__ A,
                         f16* __restrict__ W1t, f16* __restrict__ W2t,
                         f16* __restrict__ W3t)
{
  __shared__ float t[64][65];
  const int b = blockIdx.x;
  if (b < 2048) {
    const int S1 = NB * 64;
    const int S2 = S1 + NB;
    const int S3 = S2 + NB * 32;
    const int S4 = S3 + NB * 128;
    for (int i = b * blockDim.x + threadIdx.x; i < S4; i += 2048 * blockDim.x) {
      if (i < S1) {
        z[i] = T[i];
      } else if (i < S2) {
        ld[i - S1] = 0.0f;
      } else if (i < S3) {
        int r = i - S2;
        int row = r >> 5, j = r & 31;
        A[(size_t)row * AK + j] = (f16)T[row * 64 + 32 + j];
      } else {
        int r = i - S3;
        int row = r >> 7, j = r & 127;
        A[(size_t)row * AK + 32 + j] = (f16)cond[r];
      }
    }
  } else if (b < 2048 + 288) {
    const int l = b - 2048;                      // 16 x 3 x 6
    wtrans_tile(W1, W1t, AK, 1024, l % 16, (l / 16) % 3, l / 48, t);
  } else if (b < 2048 + 288 + 1536) {
    const int l = b - (2048 + 288);              // 16 x 16 x 6
    wtrans_tile(W2, W2t, HID, 1024, l % 16, (l / 16) % 16, l / 256, t);
  } else {
    const int l = b - (2048 + 288 + 1536);       // 1 x 16 x 6
    wtrans_tile(W3, W3t, HID, 64, 0, l % 16, l / 16, t);
  }
}

// ---------------------------------------------------------------------------
// GEMM1 (K=160): validated R8 body, unchanged.
// ---------------------------------------------------------------------------
__global__ __launch_bounds__(256, 2)
void gemm1_full(const f16* __restrict__ A,
                const f16* __restrict__ Wt,       // 1024 x 160
                const float* __restrict__ bias,
                f16* __restrict__ C)
{
  __shared__ __align__(16) f16 As[128 * 160];     // 40 KB
  __shared__ __align__(16) f16 Bs[128 * 160];     // 40 KB
  const int tid  = threadIdx.x;
  const int lane = tid & 63;
  const int wave = tid >> 6;
  const int c15  = lane & 15;
  const int quad = lane >> 4;
  const int wm = (wave & 1) * 64;
  const int wn = (wave >> 1) * 64;

  const int b = blockIdx.x;
  const int x = b & 7, i = b >> 3;
  const long rowStart = (long)(x * 32 + (i >> 3)) * 128;
  const long colStart = (long)(i & 7) * 128;

  const f16* Ab = A  + rowStart * AK;
  const f16* Bb = Wt + colStart * AK;

#pragma unroll
  for (int it = 0; it < 10; ++it) {
    const int f = it * 256 + tid;
    const int row = f / 20;
    const int ch  = f - row * 20;
    const int chs = ch ^ ((row >> 1) & 3);
    async_copy16(Ab + (long)row * AK + chs * 8, &As[0] + (long)f * 8);
    async_copy16(Bb + (long)row * AK + chs * 8, &Bs[0] + (long)f * 8);
  }
  __syncthreads();

  f32x4 acc[4][4] = {};
#pragma unroll
  for (int kt = 0; kt < 5; ++kt) {
    f16x8 a[4], bf[4];
#pragma unroll
    for (int mi = 0; mi < 4; ++mi) {
      const int R = wm + mi * 16 + c15;
      a[mi] = *(const f16x8*)&As[(R * 20 + kt * 4 + (quad ^ ((R >> 1) & 3))) * 8];
    }
#pragma unroll
    for (int ni = 0; ni < 4; ++ni) {
      const int R = wn + ni * 16 + c15;
      bf[ni] = *(const f16x8*)&Bs[(R * 20 + kt * 4 + (quad ^ ((R >> 1) & 3))) * 8];
    }
#pragma unroll
    for (int mi = 0; mi < 4; ++mi)
#pragma unroll
      for (int ni = 0; ni < 4; ++ni)
        acc[mi][ni] = __builtin_amdgcn_mfma_f32_16x16x32_f16(
            a[mi], bf[ni], acc[mi][ni], 0, 0, 0);
  }

#pragma unroll
  for (int ni = 0; ni < 4; ++ni) {
    const long gn = colStart + wn + ni * 16 + c15;
    const float bv = bias[gn];
#pragma unroll
    for (int mi = 0; mi < 4; ++mi) {
#pragma unroll
      for (int r = 0; r < 4; ++r) {
        const long gm = rowStart + wm + mi * 16 + quad * 4 + r;
        float v = acc[mi][ni][r] + bv;
        v = fmaxf(v, 0.0f);
        C[gm * HID + gn] = (f16)v;
      }
    }
  }
}

// ---------------------------------------------------------------------------
// GEMM2 R17: 256x256 tile, BK=32, 8 waves, 64 KB LDS dbuf -> 2 blocks/CU
// (R14-R16 post-mortem: 128 KB forced 1 block/CU, so every barrier was a
// chip-wide stall; MfmaUtil pinned 33% across 3 schedules. The 8-phase /
// deep-vmcnt family also showed absmax drift (0.25->0.72) = latent race;
// abandoned). Single-phase schedule, hazard proof:
//   - reads of buf[sel] are lgkm-drained BEFORE the barrier -> stage into
//     buf[sel] after the barrier can never race a read.
//   - in-flight DMA during kt's reads targets buf[sel^1] only (disjoint).
//   - vmcnt(4) at end of kt guarantees stage(kt+1) landed before kt+1 reads.
//   - tail: clamped stage(31) re-writes identical bytes (harmless).
// Addressing = gemm12's production-validated (row>>1)&3 XOR swizzle
// (SQ_LDS_BANK_CONFLICT measured 0). Accumulation order identical to R14 ->
// absmax must return to 0.25 exactly (race canary).
// ---------------------------------------------------------------------------
__global__ __launch_bounds__(512, 2)
void gemm2_sp(const f16* __restrict__ A,          // 32768 x 1024 (X1)
              const f16* __restrict__ Wt,         // 1024 x 1024 (n-major)
              const float* __restrict__ bias,
              f16* __restrict__ C)                // 32768 x 1024 (X2)
{
  __shared__ __align__(16) f16 As[2][8192];       // 2 x 256x32 = 32 KB
  __shared__ __align__(16) f16 Bs[2][8192];       // 32 KB

  const int tid  = threadIdx.x;
  const int lane = tid & 63;
  const int wave = tid >> 6;
  const int c15  = lane & 15;
  const int quad = lane >> 4;
  const int wm = (wave >> 2) * 128;               // wave row base in tile
  const int wn = (wave & 3) * 64;                 // wave col base in tile

  // Bijective XCD swizzle (512 blocks % 8 == 0): 64 blocks/XCD = 2/CU.
  const int b = blockIdx.x;
  const int wgid = (b & 7) * 64 + (b >> 3);
  const long rowStart = (long)(wgid >> 2) * 256;
  const long colStart = (long)(wgid & 3) * 256;

  const f16* Ab = A  + rowStart * HID;
  const f16* Bb = Wt + colStart * HID;

  // Staging: K-tile = 256 rows x 32 f16 = 1024 chunks of 16B per matrix.
  // Thread covers chunks tid (rows 0-127) and 512+tid (rows 128-255).
  // Global src pre-swizzled by (row>>1)&3; LDS dest linear.
  const int r0  = tid >> 2;
  const int ch0 = tid & 3;
  const long g0 = (long)r0 * HID + (((ch0 ^ ((r0 >> 1) & 3))) << 3);
  // rows 128-255: (row>>1)&3 identical ((128+r0)>>1 = 64+(r0>>1), 64%4==0)
  const int l0 = tid << 3;                        // chunk*8 f16

  auto stageFull = [&](int kt2, int sel) {
    const f16* sa = Ab + (long)kt2 * 32;
    const f16* sb = Bb + (long)kt2 * 32;
    f16* da = &As[sel][0];
    f16* db = &Bs[sel][0];
    async_copy16(sa + g0,                  da + l0);
    async_copy16(sa + (long)128 * HID + g0, da + 4096 + l0);
    async_copy16(sb + g0,                  db + l0);
    async_copy16(sb + (long)128 * HID + g0, db + 4096 + l0);
  };

  stageFull(0, 0);
  stageFull(1, 1);
  asm volatile("s_waitcnt vmcnt(4)" ::: "memory");   // kt0 landed
  __builtin_amdgcn_s_barrier();
  __builtin_amdgcn_sched_barrier(0);

  f32x4 acc[8][4] = {};

#pragma unroll 2
  for (int kt = 0; kt < 32; ++kt) {
    const int sel = kt & 1;
    const f16* as = &As[sel][0];
    const f16* bs = &Bs[sel][0];
    const int ktp2 = (kt + 2 < 32) ? kt + 2 : 31;    // clamped dead-fill

    f16x8 a[8], bf[4];
#pragma unroll
    for (int m = 0; m < 8; ++m) {
      const int r = wm + m * 16 + c15;
      a[m] = *(const f16x8*)&as[r * 32 + ((quad ^ ((r >> 1) & 3)) << 3)];
    }
#pragma unroll
    for (int n = 0; n < 4; ++n) {
      const int r = wn + n * 16 + c15;
      bf[n] = *(const f16x8*)&bs[r * 32 + ((quad ^ ((r >> 1) & 3)) << 3)];
    }
    asm volatile("s_waitcnt lgkmcnt(0)" ::: "memory");  // own reads done
    __builtin_amdgcn_s_barrier();                       // ALL reads done
    stageFull(ktp2, sel);                               // overwrite safe now
    __builtin_amdgcn_sched_barrier(0);
    __builtin_amdgcn_s_setprio(1);
#pragma unroll
    for (int m = 0; m < 8; ++m)
#pragma unroll
      for (int n = 0; n < 4; ++n)
        acc[m][n] = __builtin_amdgcn_mfma_f32_16x16x32_f16(
            a[m], bf[n], acc[m][n], 0, 0, 0);
    __builtin_amdgcn_s_setprio(0);
    __builtin_amdgcn_sched_barrier(0);
    asm volatile("s_waitcnt vmcnt(4)" ::: "memory");    // kt+1 landed
    __builtin_amdgcn_s_barrier();
  }

  // Epilogue: bias + relu + f16 store.
#pragma unroll
  for (int n = 0; n < 4; ++n) {
    const long gn = colStart + wn + n * 16 + c15;
    const float bv = bias[gn];
#pragma unroll
    for (int m = 0; m < 8; ++m) {
#pragma unroll
      for (int r = 0; r < 4; ++r) {
        const long gm = rowStart + wm + m * 16 + quad * 4 + r;
        float v = acc[m][n][r] + bv;
        C[gm * HID + gn] = (f16)fmaxf(v, 0.0f);
      }
    }
  }
}

// ---------------------------------------------------------------------------
// GEMM3 (N=64) + coupling epilogue — R13 validated body, unchanged.
// ---------------------------------------------------------------------------
__global__ __launch_bounds__(256, 2)
void gemm3_coupling(const f16* __restrict__ X2, const f16* __restrict__ W3t,
                    const float* __restrict__ b3, float* __restrict__ z,
                    float* __restrict__ log_det, f16* __restrict__ Anext,
                    const int maskoff)
{
  __shared__ __align__(16) f16 As[2][64 * 64];    // 8 KB per buffer
  __shared__ __align__(16) f16 Bs[2][64 * 64];
  const int tid = threadIdx.x;
  const int wave = tid >> 6, lane = tid & 63;
  const int c15 = lane & 15, quad = lane >> 4;
  const int wm = wave * 16;
  const long rowStart = (long)blockIdx.x * 64;

  const f16* Ab = X2 + rowStart * HID;
  const int brow = tid >> 3;                       // 0..31 (+q*32)
  const int bkc  = ((tid & 7) ^ (brow & 7)) * 8;

  f32x4 acc[4] = {};

  auto stage = [&](int c, int sel) {
    const long kb = (long)c * 64;
#pragma unroll
    for (int q = 0; q < 2; ++q) {
      async_copy16(Ab  + (long)(q * 32 + brow) * HID + kb + bkc,
                   &As[sel][0] + (q * 256 + wave * 64) * 8);
      async_copy16(W3t + (long)(q * 32 + brow) * HID + kb + bkc,
                   &Bs[sel][0] + (q * 256 + wave * 64) * 8);
    }
  };

  stage(0, 0);
  for (int c = 0; c < 16; ++c) {
    __syncthreads();                 // drains stage(c), issued one step ago
    if (c + 1 < 16) stage(c + 1, (c + 1) & 1);
    const f16* as = &As[c & 1][0];
    const f16* bs = &Bs[c & 1][0];

#pragma unroll
    for (int s = 0; s < 2; ++s) {
      const int Ra = wm + c15;
      f16x8 a = *(const f16x8*)&as[(Ra * 8 + ((s * 4 + quad) ^ (Ra & 7))) * 8];
      f16x8 bf[4];
#pragma unroll
      for (int ni = 0; ni < 4; ++ni) {
        const int R = ni * 16 + c15;
        bf[ni] = *(const f16x8*)&bs[(R * 8 + ((s * 4 + quad) ^ (R & 7))) * 8];
      }
#pragma unroll
      for (int ni = 0; ni < 4; ++ni)
        acc[ni] = __builtin_amdgcn_mfma_f32_16x16x32_f16(a, bf[ni], acc[ni], 0, 0, 0);
    }
  }

  float sp[4] = {0.0f, 0.0f, 0.0f, 0.0f};
#pragma unroll
  for (int ni = 0; ni < 2; ++ni) {
    const int j = ni * 16 + c15;          // s-column 0..31
    const float bs = b3[j];
    const float bt = b3[32 + j];
#pragma unroll
    for (int r = 0; r < 4; ++r) {
      const long gm = rowStart + wm + quad * 4 + r;
      const float sv = acc[ni][r] + bs;
      const float e2 = __expf(2.0f * sv);            // tanh via exp
      const float s  = 1.0f - 2.0f / (e2 + 1.0f);
      const float tv = acc[ni + 2][r] + bt;
      const float m  = z[gm * 64 + maskoff + j];
      const float y  = fmaf(m, __expf(s), tv);
      z[gm * 64 + maskoff + j] = y;
      Anext[gm * AK + j] = (f16)y;   // next layer's unmasked input
      sp[r] += s;
    }
  }
#pragma unroll
  for (int r = 0; r < 4; ++r) {
    float v = sp[r];
    v += __shfl_xor(v, 1);
    v += __shfl_xor(v, 2);
    v += __shfl_xor(v, 4);
    v += __shfl_xor(v, 8);
    if (c15 == 0) {
      const long gm = rowStart + wm + quad * 4 + r;
      log_det[gm] += v;   // only this thread touches this row this layer
    }
  }
}

// ---------------------------------------------------------------------------
extern "C" void kernel_launch(void* const* d_in, const int* in_sizes, int n_in,
                              void* d_out, int out_size, void* d_ws, size_t ws_size,
                              hipStream_t stream) {
  (void)in_sizes; (void)n_in; (void)out_size; (void)ws_size;
  const float* T    = (const float*)d_in[0];
  const float* cond = (const float*)d_in[1];
  const float* W1   = (const float*)d_in[2];
  const float* b1   = (const float*)d_in[3];
  const float* W2   = (const float*)d_in[4];
  const float* b2   = (const float*)d_in[5];
  const float* W3   = (const float*)d_in[6];
  const float* b3   = (const float*)d_in[7];

  float* z  = (float*)d_out;                 // B x 64 working state = output
  float* ld = z + (size_t)NB * 64;           // B log_det

  f16* A   = (f16*)d_ws;                     // B x 160
  f16* X1  = A   + (size_t)NB * AK;          // B x 1024
  f16* X2  = X1  + (size_t)NB * HID;         // B x 1024
  f16* W1t = X2  + (size_t)NB * HID;         // 6 x 1024 x 160
  f16* W2t = W1t + (size_t)6 * 1024 * 160;   // 6 x 1024 x 1024
  f16* W3t = W2t + ((size_t)6 << 20);        // 6 x 64 x 1024

  prep_all<<<3968, 256, 0, stream>>>(T, cond, W1, W2, W3,
                                     z, ld, A, W1t, W2t, W3t);

  const int g1 = (NB / 128) * (HID / 128);   // 2048 blocks
  const int g2 = (NB / 256) * (HID / 256);   // 512 blocks
  for (int l = 0; l < LAYERS; ++l) {
    gemm1_full<<<g1, 256, 0, stream>>>(A, W1t + (size_t)l * 1024 * AK,
                                       b1 + l * 1024, X1);
    gemm2_sp<<<g2, 512, 0, stream>>>(X1, W2t + ((size_t)l << 20),
                                     b2 + l * 1024, X2);
    const int maskoff = (l & 1) ? 32 : 0;
    gemm3_coupling<<<NB / 64, 256, 0, stream>>>(X2, W3t + (size_t)l * 64 * 1024,
                                                b3 + l * 64, z, ld, A, maskoff);
  }
}